// Round 9
// baseline (366.427 us; speedup 1.0000x reference)
//
#include <hip/hip_runtime.h>
#include <hip/hip_bf16.h>

using short8 = __attribute__((ext_vector_type(8))) short;
using f32x16 = __attribute__((ext_vector_type(16))) float;
using u32x4  = __attribute__((ext_vector_type(4))) unsigned int;

#define DDIM 512
#define NROWS 1024
#define CCLS 100000
#define NCT 782            // c-tiles of 128
#define CPAD (NCT * 128)   // 100096 (winv zero-padded)
#define GRID_BLOCKS 768    // 3/CU co-resident, persistent

__device__ inline unsigned int f2bf(float f) {
    unsigned int u = __float_as_uint(f);
    u += 0x7FFFu + ((u >> 16) & 1u);
    return u >> 16;
}

__device__ inline unsigned int pk2(float x, float y) {
    unsigned int r;
    asm("v_cvt_pk_bf16_f32 %0, %1, %2" : "=v"(r) : "v"(x), "v"(y));
    return r;
}

__device__ inline void gload_lds16(const void* g, void* l) {
    __builtin_amdgcn_global_load_lds(
        (const __attribute__((address_space(1))) void*)g,
        (__attribute__((address_space(3))) void*)l, 16, 0, 0);
}

// ---------------- kernel 1: normalize x rows -> bf16 ----------------
__global__ __launch_bounds__(256) void norm_x(const float* __restrict__ x,
                                              unsigned short* __restrict__ xn) {
    const int row = blockIdx.x;
    const int tid = threadIdx.x;
    float2 v = *(const float2*)(x + (size_t)row * DDIM + tid * 2);
    float ss = v.x * v.x + v.y * v.y;
#pragma unroll
    for (int m = 1; m < 64; m <<= 1) ss += __shfl_xor(ss, m);
    __shared__ float wsum[4];
    if ((tid & 63) == 0) wsum[tid >> 6] = ss;
    __syncthreads();
    float inv = 1.0f / sqrtf(wsum[0] + wsum[1] + wsum[2] + wsum[3]);
    unsigned int packed = f2bf(v.x * inv) | (f2bf(v.y * inv) << 16);
    ((unsigned int*)xn)[(size_t)row * (DDIM / 2) + tid] = packed;
}

// ---------------- kernel 2: per-class inverse norm (warms L3 with W) --------
__global__ __launch_bounds__(256) void norm_w(const float* __restrict__ W,
                                              float* __restrict__ winv) {
    const int row  = blockIdx.x * 4 + (threadIdx.x >> 6);
    const int lane = threadIdx.x & 63;
    if (row < CCLS) {
        const float4* p = (const float4*)(W + (size_t)row * DDIM + lane * 8);
        float4 a = p[0], b = p[1];
        float ss = a.x*a.x + a.y*a.y + a.z*a.z + a.w*a.w
                 + b.x*b.x + b.y*b.y + b.z*b.z + b.w*b.w;
#pragma unroll
        for (int m = 1; m < 64; m <<= 1) ss += __shfl_xor(ss, m);
        if (lane == 0) winv[row] = (ss > 0.0f) ? (1.0f / sqrtf(ss)) : 0.0f;
    } else if (lane == 0) {
        winv[row] = 0.0f;
    }
}

// ---------------- kernel 3: GEMM (32x32x16 MFMA) + exp-rowsum + target ------
// 128(m) x 128(c) tile, BK=64, 4 waves (2x2), per wave 64x64 = 2x2 frags of
// 32x32 (acc[2][2] f32x16). 32x32x16 does 2x the FLOPs per operand byte of
// 16x16x32 -> LDS-pipe time per MFMA halves (R8 was LDS-traffic-bound).
// Staging is pure DMA (A bf16 16KB + W f32 32KB, pre-swizzled sources,
// linear dest); compute is pure LDS (ds_read_b128 + cvt_pk + MFMA).
// W swizzle now XORs the full 16-slot row (&15): 2-way max, free.
__global__ __launch_bounds__(256, 4) void arc_gemm(
    const unsigned short* __restrict__ xn,   // [1024][512] bf16
    const float* __restrict__ W,             // [C][512] f32
    const float* __restrict__ winv,          // [CPAD]
    const int* __restrict__ labels,          // [1024]
    float* __restrict__ rowsum,              // [1024] (pre-zeroed)
    float* __restrict__ tcos)                // [1024]
{
    __shared__ __align__(16) unsigned short lsA[128 * 64]; // 16 KB
    __shared__ __align__(16) float          lsW[128 * 64]; // 32 KB
    __shared__ float lrow[128];
    __shared__ int   llab[128];

    const int tid  = threadIdx.x;
    const int lane = tid & 63;
    const int wid  = tid >> 6;
    const int wr   = wid >> 1, wc = wid & 1;
    const int h    = lane >> 5;
    const int ln31 = lane & 31;

    // A DMA: 4 insts cover 128 rows x 8 slots(16B); source col pre-swizzled
    const int arow = tid >> 3;
    const int acol = ((tid & 7) ^ (arow & 7)) * 8;      // bf16 units
    // W DMA: 8 insts cover 128 rows x 16 slots(16B); full &15 XOR
    const int wrow = tid >> 4;
    const int wcol = ((tid & 15) ^ (wrow & 15)) * 4;    // f32 units

    const int x    = blockIdx.x & 7;
    const int sidx = blockIdx.x >> 3;       // 0..95 within XCD window
    const int nct  = (NCT - 1 - x) / 8 + 1;
    const int npairs = nct * 8;

    for (int p = sidx; p < npairs; p += GRID_BLOCKS / 8) {
        const int ct = x + 8 * (p >> 3);
        const int mt = p & 7;
        const int c0 = ct * 128;
        const int m0 = mt * 128;

        if (tid < 128) { lrow[tid] = 0.0f; llab[tid] = labels[m0 + tid]; }

        f32x16 acc[2][2];
#pragma unroll
        for (int i = 0; i < 2; ++i)
#pragma unroll
            for (int j = 0; j < 2; ++j) acc[i][j] = (f32x16)(0.0f);

#pragma unroll 1
        for (int k = 0; k < 8; ++k) {
            const int k0 = k * 64;
            __syncthreads();   // prev compute done; also publishes llab/lrow
#pragma unroll
            for (int it = 0; it < 4; ++it)
                gload_lds16(xn + (size_t)(m0 + it * 32 + arow) * DDIM + k0 + acol,
                            (char*)lsA + (it * 256 + wid * 64) * 16);
#pragma unroll
            for (int it = 0; it < 8; ++it) {
                int c = c0 + it * 16 + wrow;
                if (c > CCLS - 1) c = CCLS - 1;   // clamp; masked in epilogue
                gload_lds16(W + (size_t)c * DDIM + k0 + wcol,
                            (char*)lsW + (it * 256 + wid * 64) * 16);
            }
            __syncthreads();   // vmcnt drain -> tiles ready

#pragma unroll
            for (int ks = 0; ks < 4; ++ks) {
                short8 af[2], bg[2];
#pragma unroll
                for (int i = 0; i < 2; ++i) {
                    int r = wr * 64 + i * 32 + ln31;
                    af[i] = *(const short8*)((const char*)lsA
                            + r * 128 + ((((ks << 1) + h) ^ (r & 7)) << 4));
                }
#pragma unroll
                for (int j = 0; j < 2; ++j) {
                    int rc = wc * 64 + j * 32 + ln31;
                    int t2 = ((ks << 1) + h) << 1;
                    const char* base = (const char*)lsW + rc * 256;
                    float4 v0 = *(const float4*)(base + (((t2    ) ^ (rc & 15)) << 4));
                    float4 v1 = *(const float4*)(base + (((t2 + 1) ^ (rc & 15)) << 4));
                    u32x4 u = { pk2(v0.x, v0.y), pk2(v0.z, v0.w),
                                pk2(v1.x, v1.y), pk2(v1.z, v1.w) };
                    bg[j] = __builtin_bit_cast(short8, u);
                }
#pragma unroll
                for (int i = 0; i < 2; ++i)
#pragma unroll
                    for (int j = 0; j < 2; ++j)
                        acc[i][j] = __builtin_amdgcn_mfma_f32_32x32x16_bf16(
                            af[i], bg[j], acc[i][j], 0, 0, 0);
            }
        }

        // ---- epilogue: cos = acc*winv; exp-sum; target capture ----
        // C/D 32x32 layout: col = lane&31, row = (reg&3) + 8*(reg>>2) + 4*h
        float wv[2]; int cj[2];
#pragma unroll
        for (int j = 0; j < 2; ++j) {
            cj[j] = c0 + wc * 64 + j * 32 + ln31;
            wv[j] = winv[cj[j]];
        }
#pragma unroll
        for (int i = 0; i < 2; ++i) {
#pragma unroll
            for (int r = 0; r < 16; ++r) {
                const int rl  = wr * 64 + i * 32 + ((r & 3) + 8 * (r >> 2) + 4 * h);
                const int lab = llab[rl];
                float sm = 0.0f;
#pragma unroll
                for (int j = 0; j < 2; ++j) {
                    float cv = acc[i][j][r] * wv[j];
                    if (cj[j] < CCLS) sm += __expf(64.0f * cv);
                    if (cj[j] == lab) tcos[m0 + rl] = cv;
                }
                sm += __shfl_xor(sm, 1);
                sm += __shfl_xor(sm, 2);
                sm += __shfl_xor(sm, 4);
                sm += __shfl_xor(sm, 8);
                sm += __shfl_xor(sm, 16);
                if (ln31 == 0) atomicAdd(&lrow[rl], sm);
            }
        }
        __syncthreads();
        if (tid < 128) atomicAdd(&rowsum[m0 + tid], lrow[tid]);
        // next pair rewrites lrow/llab (same-thread ordering + k-loop barrier)
    }
}

// ---------------- kernel 4: final loss ----------------
__global__ __launch_bounds__(256) void arc_final(const float* __restrict__ rowsum,
                                                 const float* __restrict__ tcos,
                                                 float* __restrict__ out) {
    const int tid = threadIdx.x;
    const float cosM = 0.87758256189037271612f;  // cos(0.5)
    const float sinM = 0.47942553860420300027f;  // sin(0.5)
    float L = 0.0f;
    for (int n = tid; n < NROWS; n += 256) {
        float tc  = tcos[n];
        float tcl = fminf(fmaxf(tc, -1.0f + 1e-7f), 1.0f - 1e-7f);
        float num = 64.0f * (tcl * cosM - sinM * sqrtf(fmaxf(0.0f, 1.0f - tcl * tcl)));
        float den = __expf(num) + rowsum[n] - __expf(64.0f * tc);
        L += num - logf(den);
    }
    __shared__ float red[256];
    red[tid] = L;
    __syncthreads();
    for (int s = 128; s > 0; s >>= 1) {
        if (tid < s) red[tid] += red[tid + s];
        __syncthreads();
    }
    if (tid == 0) out[0] = -(red[0] / (float)NROWS);
}

// ---------------- launch ----------------
extern "C" void kernel_launch(void* const* d_in, const int* in_sizes, int n_in,
                              void* d_out, int out_size, void* d_ws, size_t ws_size,
                              hipStream_t stream) {
    const float* x      = (const float*)d_in[0];
    const float* W      = (const float*)d_in[1];
    const int*   labels = (const int*)d_in[2];
    float* out = (float*)d_out;
    char*  ws  = (char*)d_ws;

    unsigned short* xn = (unsigned short*)(ws);                 // 1,048,576 B
    float* winv        = (float*)(ws + 1048576);                // 400,384 B
    float* rowsum      = (float*)(ws + 1048576 + 400384);       // 4,096 B
    float* tcos        = (float*)(ws + 1048576 + 400384 + 4096);// 4,096 B

    (void)hipMemsetAsync(rowsum, 0, NROWS * sizeof(float), stream);

    norm_x<<<NROWS, 256, 0, stream>>>(x, xn);
    norm_w<<<CPAD / 4, 256, 0, stream>>>(W, winv);

    arc_gemm<<<GRID_BLOCKS, 256, 0, stream>>>(xn, W, winv, labels, rowsum, tcos);

    arc_final<<<1, 256, 0, stream>>>(rowsum, tcos, out);
}

// Round 10
// 179.807 us; speedup vs baseline: 2.0379x; 2.0379x over previous
//
#include <hip/hip_runtime.h>
#include <hip/hip_bf16.h>

using short8 = __attribute__((ext_vector_type(8))) short;
using f32x4  = __attribute__((ext_vector_type(4))) float;
using u32x4  = __attribute__((ext_vector_type(4))) unsigned int;

#define DDIM 512
#define NROWS 1024
#define CCLS 100000
#define NCT 782            // c-tiles of 128
#define CPAD (NCT * 128)   // 100096 padded classes
#define GRID_BLOCKS 1024   // 4/CU, persistent XCD-windowed

__device__ inline unsigned int f2bf(float f) {
    unsigned int u = __float_as_uint(f);
    u += 0x7FFFu + ((u >> 16) & 1u);
    return u >> 16;
}

__device__ inline unsigned int pk2(float x, float y) {
    unsigned int r;
    asm("v_cvt_pk_bf16_f32 %0, %1, %2" : "=v"(r) : "v"(x), "v"(y));
    return r;
}

__device__ inline void gload_lds16(const void* g, void* l) {
    __builtin_amdgcn_global_load_lds(
        (const __attribute__((address_space(1))) void*)g,
        (__attribute__((address_space(3))) void*)l, 16, 0, 0);
}

// ---------------- kernel 1: normalize x rows -> bf16 ----------------
__global__ __launch_bounds__(256) void norm_x(const float* __restrict__ x,
                                              unsigned short* __restrict__ xn) {
    const int row = blockIdx.x;
    const int tid = threadIdx.x;
    float2 v = *(const float2*)(x + (size_t)row * DDIM + tid * 2);
    float ss = v.x * v.x + v.y * v.y;
#pragma unroll
    for (int m = 1; m < 64; m <<= 1) ss += __shfl_xor(ss, m);
    __shared__ float wsum[4];
    if ((tid & 63) == 0) wsum[tid >> 6] = ss;
    __syncthreads();
    float inv = 1.0f / sqrtf(wsum[0] + wsum[1] + wsum[2] + wsum[3]);
    unsigned int packed = f2bf(v.x * inv) | (f2bf(v.y * inv) << 16);
    ((unsigned int*)xn)[(size_t)row * (DDIM / 2) + tid] = packed;
}

// ------- kernel 2a: W -> bf16 copy + inverse norms (one wave per row) -------
__global__ __launch_bounds__(256) void norm_w_cvt(const float* __restrict__ W,
                                                  unsigned short* __restrict__ Wbf,
                                                  float* __restrict__ winv) {
    const int row  = blockIdx.x * 4 + (threadIdx.x >> 6);
    const int lane = threadIdx.x & 63;
    if (row < CCLS) {
        const float4* p = (const float4*)(W + (size_t)row * DDIM + lane * 8);
        float4 a = p[0], b = p[1];
        float ss = a.x*a.x + a.y*a.y + a.z*a.z + a.w*a.w
                 + b.x*b.x + b.y*b.y + b.z*b.z + b.w*b.w;
        u32x4 u = { pk2(a.x, a.y), pk2(a.z, a.w), pk2(b.x, b.y), pk2(b.z, b.w) };
        *(u32x4*)(Wbf + (size_t)row * DDIM + lane * 8) = u;
#pragma unroll
        for (int m = 1; m < 64; m <<= 1) ss += __shfl_xor(ss, m);
        if (lane == 0) winv[row] = (ss > 0.0f) ? (1.0f / sqrtf(ss)) : 0.0f;
    } else {
        *(u32x4*)(Wbf + (size_t)row * DDIM + lane * 8) = u32x4{0u, 0u, 0u, 0u};
        if (lane == 0) winv[row] = 0.0f;
    }
}

// ------- kernel 2b (fallback): inverse norms only --------------------------
__global__ __launch_bounds__(256) void norm_w(const float* __restrict__ W,
                                              float* __restrict__ winv) {
    const int row  = blockIdx.x * 4 + (threadIdx.x >> 6);
    const int lane = threadIdx.x & 63;
    if (row < CCLS) {
        const float4* p = (const float4*)(W + (size_t)row * DDIM + lane * 8);
        float4 a = p[0], b = p[1];
        float ss = a.x*a.x + a.y*a.y + a.z*a.z + a.w*a.w
                 + b.x*b.x + b.y*b.y + b.z*b.z + b.w*b.w;
#pragma unroll
        for (int m = 1; m < 64; m <<= 1) ss += __shfl_xor(ss, m);
        if (lane == 0) winv[row] = (ss > 0.0f) ? (1.0f / sqrtf(ss)) : 0.0f;
    } else if (lane == 0) {
        winv[row] = 0.0f;
    }
}

// ---------------- kernel 3: GEMM + exp-rowsum + target ----------------------
// 128(m) x 128(c) tile, BK=64, 4 waves (2x2), acc[4][4], 16x16x32 MFMA.
// BF16W=true: both operands bf16, pure-DMA staging (16KB+16KB/k-step),
//   conflict-free 16-row fr reads (R1-proven), zero VALU in staging,
//   zero cvt in compute. LDS 33KB -> 4 blocks/CU.
// BF16W=false: W staged f32 (32KB) with full &15 XOR, cvt_pk in compute.
template <bool BF16W>
__global__ __launch_bounds__(256, BF16W ? 4 : 3) void arc_gemm(
    const unsigned short* __restrict__ xn,   // [1024][512] bf16
    const void* __restrict__ Wsrc,           // bf16 [CPAD][512] or f32 [C][512]
    const float* __restrict__ winv,          // [CPAD]
    const int* __restrict__ labels,          // [1024]
    float* __restrict__ rowsum,              // [1024] (pre-zeroed)
    float* __restrict__ tcos)                // [1024]
{
    __shared__ __align__(16) char smem[BF16W ? 32768 : 49152];
    __shared__ float lrow[128];
    __shared__ int   llab[128];
    char* lsA = smem;            // 16 KB bf16 A
    char* lsW = smem + 16384;    // 16 KB bf16 W  or 32 KB f32 W

    const int tid  = threadIdx.x;
    const int lane = tid & 63;
    const int wid  = tid >> 6;
    const int wr   = wid >> 1, wc = wid & 1;
    const int q    = lane >> 4;
    const int fr   = lane & 15;

    // bf16 DMA geometry (A always; W when BF16W): 128 rows x 8 slots(16B)
    const int arow = tid >> 3;
    const int acol = ((tid & 7) ^ (arow & 7)) * 8;      // bf16 units
    // f32 W DMA geometry: 128 rows x 16 slots(16B), full &15 XOR
    const int wrow = tid >> 4;
    const int wcol = ((tid & 15) ^ (wrow & 15)) * 4;    // f32 units

    const int x    = blockIdx.x & 7;
    const int sidx = blockIdx.x >> 3;
    const int nct  = (NCT - 1 - x) / 8 + 1;
    const int npairs = nct * 8;

    for (int p = sidx; p < npairs; p += GRID_BLOCKS / 8) {
        const int ct = x + 8 * (p >> 3);
        const int mt = p & 7;
        const int c0 = ct * 128;
        const int m0 = mt * 128;

        if (tid < 128) { lrow[tid] = 0.0f; llab[tid] = labels[m0 + tid]; }

        f32x4 acc[4][4];
#pragma unroll
        for (int i = 0; i < 4; ++i)
#pragma unroll
            for (int j = 0; j < 4; ++j) acc[i][j] = (f32x4)(0.0f);

#pragma unroll 1
        for (int k = 0; k < 8; ++k) {
            const int k0 = k * 64;
            __syncthreads();   // prev compute done; publishes llab/lrow
#pragma unroll
            for (int it = 0; it < 4; ++it)
                gload_lds16(xn + (size_t)(m0 + it * 32 + arow) * DDIM + k0 + acol,
                            lsA + (it * 256 + wid * 64) * 16);
            if constexpr (BF16W) {
                const unsigned short* Wb = (const unsigned short*)Wsrc;
#pragma unroll
                for (int it = 0; it < 4; ++it)
                    gload_lds16(Wb + (size_t)(c0 + it * 32 + arow) * DDIM + k0 + acol,
                                lsW + (it * 256 + wid * 64) * 16);
            } else {
                const float* Wf = (const float*)Wsrc;
#pragma unroll
                for (int it = 0; it < 8; ++it) {
                    int c = c0 + it * 16 + wrow;
                    if (c > CCLS - 1) c = CCLS - 1;
                    gload_lds16(Wf + (size_t)c * DDIM + k0 + wcol,
                                lsW + (it * 256 + wid * 64) * 16);
                }
            }
            __syncthreads();   // vmcnt drain -> tiles ready

#pragma unroll
            for (int ks = 0; ks < 2; ++ks) {
                short8 af[4], bg[4];
#pragma unroll
                for (int i = 0; i < 4; ++i) {
                    int r = wr * 64 + i * 16 + fr;
                    af[i] = *(const short8*)(lsA
                            + r * 128 + (((ks * 4 + q) ^ (r & 7)) << 4));
                }
#pragma unroll
                for (int j = 0; j < 4; ++j) {
                    int rc = wc * 64 + j * 16 + fr;
                    if constexpr (BF16W) {
                        bg[j] = *(const short8*)(lsW
                                + rc * 128 + (((ks * 4 + q) ^ (rc & 7)) << 4));
                    } else {
                        int t2 = (ks * 4 + q) * 2;
                        const char* base = lsW + rc * 256;
                        float4 v0 = *(const float4*)(base + (((t2    ) ^ (rc & 15)) << 4));
                        float4 v1 = *(const float4*)(base + (((t2 + 1) ^ (rc & 15)) << 4));
                        u32x4 u = { pk2(v0.x, v0.y), pk2(v0.z, v0.w),
                                    pk2(v1.x, v1.y), pk2(v1.z, v1.w) };
                        bg[j] = __builtin_bit_cast(short8, u);
                    }
                }
#pragma unroll
                for (int i = 0; i < 4; ++i)
#pragma unroll
                    for (int j = 0; j < 4; ++j)
                        acc[i][j] = __builtin_amdgcn_mfma_f32_16x16x32_bf16(
                            af[i], bg[j], acc[i][j], 0, 0, 0);
            }
        }

        // ---- epilogue: cos = acc*winv; exp-sum; target capture ----
        float wv[4]; int cj[4];
#pragma unroll
        for (int j = 0; j < 4; ++j) {
            cj[j] = c0 + wc * 64 + j * 16 + fr;
            wv[j] = winv[cj[j]];
        }
#pragma unroll
        for (int i = 0; i < 4; ++i) {
#pragma unroll
            for (int v = 0; v < 4; ++v) {
                const int rl  = wr * 64 + i * 16 + q * 4 + v;
                const int lab = llab[rl];
                float sm = 0.0f;
#pragma unroll
                for (int j = 0; j < 4; ++j) {
                    float cv = acc[i][j][v] * wv[j];
                    if (cj[j] < CCLS) sm += __expf(64.0f * cv);
                    if (cj[j] == lab) tcos[m0 + rl] = cv;
                }
                sm += __shfl_xor(sm, 1);
                sm += __shfl_xor(sm, 2);
                sm += __shfl_xor(sm, 4);
                sm += __shfl_xor(sm, 8);
                if (fr == 0) atomicAdd(&lrow[rl], sm);
            }
        }
        __syncthreads();
        if (tid < 128) atomicAdd(&rowsum[m0 + tid], lrow[tid]);
    }
}

// ---------------- kernel 4: final loss ----------------
__global__ __launch_bounds__(256) void arc_final(const float* __restrict__ rowsum,
                                                 const float* __restrict__ tcos,
                                                 float* __restrict__ out) {
    const int tid = threadIdx.x;
    const float cosM = 0.87758256189037271612f;  // cos(0.5)
    const float sinM = 0.47942553860420300027f;  // sin(0.5)
    float L = 0.0f;
    for (int n = tid; n < NROWS; n += 256) {
        float tc  = tcos[n];
        float tcl = fminf(fmaxf(tc, -1.0f + 1e-7f), 1.0f - 1e-7f);
        float num = 64.0f * (tcl * cosM - sinM * sqrtf(fmaxf(0.0f, 1.0f - tcl * tcl)));
        float den = __expf(num) + rowsum[n] - __expf(64.0f * tc);
        L += num - logf(den);
    }
    __shared__ float red[256];
    red[tid] = L;
    __syncthreads();
    for (int s = 128; s > 0; s >>= 1) {
        if (tid < s) red[tid] += red[tid + s];
        __syncthreads();
    }
    if (tid == 0) out[0] = -(red[0] / (float)NROWS);
}

// ---------------- launch ----------------
extern "C" void kernel_launch(void* const* d_in, const int* in_sizes, int n_in,
                              void* d_out, int out_size, void* d_ws, size_t ws_size,
                              hipStream_t stream) {
    const float* x      = (const float*)d_in[0];
    const float* W      = (const float*)d_in[1];
    const int*   labels = (const int*)d_in[2];
    float* out = (float*)d_out;
    char*  ws  = (char*)d_ws;

    const size_t WBF_BYTES = (size_t)CPAD * DDIM * 2;   // 102,498,304
    unsigned short* xn   = (unsigned short*)(ws);                    // 1 MB
    unsigned short* Wbf  = (unsigned short*)(ws + 1048576);
    const size_t tail    = 1048576 + WBF_BYTES;
    const bool big       = (ws_size >= tail + 512 * 1024);

    float* winv, *rowsum, *tcos;
    if (big) {
        winv   = (float*)(ws + tail);
        rowsum = (float*)(ws + tail + 4 * CPAD);
        tcos   = (float*)(ws + tail + 4 * CPAD + 4096);
    } else {
        winv   = (float*)(ws + 1048576);
        rowsum = (float*)(ws + 1048576 + 4 * CPAD);
        tcos   = (float*)(ws + 1048576 + 4 * CPAD + 4096);
    }

    (void)hipMemsetAsync(rowsum, 0, NROWS * sizeof(float), stream);

    norm_x<<<NROWS, 256, 0, stream>>>(x, xn);

    if (big) {
        norm_w_cvt<<<CPAD / 4, 256, 0, stream>>>(W, Wbf, winv);
        arc_gemm<true><<<GRID_BLOCKS, 256, 0, stream>>>(
            xn, (const void*)Wbf, winv, labels, rowsum, tcos);
    } else {
        norm_w<<<CPAD / 4, 256, 0, stream>>>(W, winv);
        arc_gemm<false><<<GRID_BLOCKS, 256, 0, stream>>>(
            xn, (const void*)W, winv, labels, rowsum, tcos);
    }

    arc_final<<<1, 256, 0, stream>>>(rowsum, tcos, out);
}